// Round 9
// baseline (323.430 us; speedup 1.0000x reference)
//
#include <hip/hip_runtime.h>

// Spatially varying anisotropic 2D elastic wave sim, 384x384, 192 steps.
// Round 16 (resubmit; previous attempt hit a container-infra failure, no
// signal). I-cache test. R15 exactly (OWN=24, HALO=K=12, TS=48, 16
// launches, 768 thr = 12 waves, 3x1 cells/thread, DPP column exchange,
// lgkm-only barrier) with ONE variable changed: the 12-step loop is
// ROLLED (#pragma unroll 1), shrinking the hot body from ~18KB
// straight-line code to ~1.3KB (I$-resident).
//  - theory: per-step stall (~2800cy vs ~450cy issue floor) is
//    instruction-fetch streaming: per-CU shared (occupancy-invariant),
//    LDS-invariant, not in VALUBusy -- matches all null results.
//  - sig values staged in a 12-float LDS table (written pre-loop,
//    covered by the initial lgkm barrier); per-step ds_read_b32 joins
//    the existing lgkm queue. No runtime-indexed private arrays remain
//    in the body (rule #20 safe: cur/old/v/dh all statically indexed).
//  - everything else bit-identical math to R15.

typedef float v2f __attribute__((ext_vector_type(2)));

#define NXg 384
#define NYg 384
#define NPT (NXg * NYg)
#define NFRAMES 48

#define OWN 24
#define HALO 12
#define TS 48
#define KSTEPS 12
#define NLAUNCH 16
#define NTH 768          // 16 wide x 48 tall threads, 12 waves
#define TROW 16

#define H_   1e-4
#define DT_  5e-9
#define RHO_ 1610.0

#define B11_LO 5e10f
#define B11_HI 2.5e11f
#define B22_LO 5e9f
#define B22_HI 5e10f
#define B12_LO 5e9f
#define B12_HI 5e10f
#define B16_LO 0.0f
#define B16_HI 6e10f
#define B26_LO 0.0f
#define B26_HI 2e10f
#define B66_LO 5e9f
#define B66_HI 3e10f

#define ROW_SHR1 0x111   // dst[lane] = src[lane-1] within 16-lane row
#define ROW_SHL1 0x101   // dst[lane] = src[lane+1] within 16-lane row

static __device__ __constant__ float kScale  = (float)(DT_ * DT_ / (H_ * H_) / RHO_);
static __device__ __constant__ float kSrcScl = (float)(DT_ * DT_ / RHO_);

__device__ __forceinline__ float clipf(float v, float lo, float hi) {
    return fminf(fmaxf(v, lo), hi);
}
__device__ __forceinline__ v2f vfma(v2f a, v2f b, v2f c) {
    return __builtin_elementwise_fma(a, b, c);
}
__device__ __forceinline__ v2f vbc(float s) { v2f r; r[0] = s; r[1] = s; return r; }
__device__ __forceinline__ v2f vswap(v2f a) { return __builtin_shufflevector(a, a, 1, 0); }

// in-wave halo import: neighbor lane's v2f via 2x v_mov_dpp.
// Invalid lanes (16-lane-row edge) receive 'oldv' == the rim-clamp value.
template <int CTRL>
__device__ __forceinline__ v2f dpp_shift(v2f oldv, v2f src) {
    union { v2f v; int i[2]; } o, s, r;
    o.v = oldv; s.v = src;
    r.i[0] = __builtin_amdgcn_update_dpp(o.i[0], s.i[0], CTRL, 0xf, 0xf, false);
    r.i[1] = __builtin_amdgcn_update_dpp(o.i[1], s.i[1], CTRL, 0xf, 0xf, false);
    return r.v;
}

// barrier that only waits LDS (no vmcnt drain); memory clobber pins ordering
#define LDS_BARRIER() asm volatile("s_waitcnt lgkmcnt(0)\n\ts_barrier" ::: "memory")

// ws float layout:
// [0..4NPT):   C0 = float4{A11, A22, A12p66, A16}  (pre-scaled)
// [4NPT..8NPT):C1 = float4{A26, A66, GS, 0}
// [8NPT..12NPT):  state set0: float4{cur.x, cur.y, old.x, old.y}
// [12NPT..16NPT): state set1

__global__ __launch_bounds__(256)
void setup_kernel(const float* __restrict__ lc11, const float* __restrict__ lc12,
                  const float* __restrict__ lc16, const float* __restrict__ lc22,
                  const float* __restrict__ lc26, const float* __restrict__ lc66,
                  const float* __restrict__ gauss, float* __restrict__ ws) {
    int i = blockIdx.x * blockDim.x + threadIdx.x;
    if (i >= NPT) return;
    float C11 = clipf(expf(lc11[i]), B11_LO, B11_HI);
    float C12 = clipf(expf(lc12[i]), B12_LO, B12_HI);
    float C16 = clipf(expf(lc16[i]), B16_LO, B16_HI);
    float C22 = clipf(expf(lc22[i]), B22_LO, B22_HI);
    float C26 = clipf(expf(lc26[i]), B26_LO, B26_HI);
    float C66 = clipf(expf(lc66[i]), B66_LO, B66_HI);
    float s = kScale;
    float4* C0 = (float4*)ws;
    float4* C1 = (float4*)(ws + 4 * (size_t)NPT);
    C0[i] = make_float4(C11 * s, C22 * s, (C12 + C66) * s, C16 * s);
    C1[i] = make_float4(C26 * s, C66 * s, gauss[i] * kSrcScl, 0.0f);
    float4* s0 = (float4*)(ws + 8 * (size_t)NPT);
    s0[i] = make_float4(0.0f, 0.0f, 0.0f, 0.0f);
}

__global__ __launch_bounds__(NTH)
void fused_kernel(const float* __restrict__ ws, const float* __restrict__ sig,
                  const float4* __restrict__ inS, float4* __restrict__ outS,
                  float* __restrict__ out, int L) {
    __shared__ v2f sb[2][TS][TS + 1];
    __shared__ float sigl[KSTEPS];

    const int tid = threadIdx.x;
    const int tx = tid >> 4;          // 0..47 cell row
    const int ty = tid & 15;          // 0..15, 3 cells wide each
    const int r0 = tx;
    const int c0 = 3 * ty;
    const int gx0 = blockIdx.y * OWN - HALO;
    const int gy0 = blockIdx.x * OWN - HALO;

    const float4* __restrict__ C0 = (const float4*)ws;
    const float4* __restrict__ C1 = (const float4*)(ws + 4 * (size_t)NPT);

    v2f cur[3], old_[3];
    v2f ca[3], cb[3];                       // {A11,A66}, {A66,A22}
    float a12p66[3], a16[3], a26[3], gs[3];
    int gidx[3];

#pragma unroll
    for (int j = 0; j < 3; ++j) {
        int gx = gx0 + r0;
        int gy = gy0 + c0 + j;
        bool d = (unsigned)gx < (unsigned)NXg && (unsigned)gy < (unsigned)NYg;
        int g = d ? gx * NYg + gy : 0;
        gidx[j] = g;
        float4 st = d ? inS[g] : make_float4(0, 0, 0, 0);
        v2f c; c[0] = st.x; c[1] = st.y;
        v2f o; o[0] = st.z; o[1] = st.w;
        cur[j] = c; old_[j] = o;
        float4 k0 = d ? C0[g] : make_float4(0, 0, 0, 0);
        float4 k1 = d ? C1[g] : make_float4(0, 0, 0, 0);
        v2f t; t[0] = k0.x; t[1] = k1.y; ca[j] = t;   // {A11, A66}
        v2f u; u[0] = k1.y; u[1] = k0.y; cb[j] = u;   // {A66, A22}
        a12p66[j] = k0.z; a16[j] = k0.w; a26[j] = k1.x; gs[j] = k1.z;
    }

    // stage this launch's 12 source values into LDS (covered by the
    // initial lgkm barrier below); per-step ds_read_b32 replaces the
    // full-unroll register table -> body stays small and I$-resident.
    const int t0 = L * KSTEPS;
    if (tid < KSTEPS) sigl[tid] = sig[t0 + tid];

    // clamped vertical halo rows (trapezoid garbage-tolerance at rim)
    const int rm = (r0 > 0) ? r0 - 1 : 0;
    const int rp = (r0 + 1 < TS) ? r0 + 1 : TS - 1;

    // owned core: rows [12,36) -> tx in [12,36); cols [12,36) -> ty in [4,12)
    const bool owned = (tx >= 12) && (tx < 36) && (ty >= 4) && (ty < 12);

    // publish initial values into buffer 0
#pragma unroll
    for (int j = 0; j < 3; ++j)
        sb[0][r0][c0 + j] = cur[j];
    LDS_BARRIER();

    v2f c20; c20[0] = 2.0f; c20[1] = 0.0f;
    v2f c02; c02[0] = 0.0f; c02[1] = 2.0f;
    const v2f m2 = vbc(-2.0f);
    const v2f qt = vbc(0.25f);
    const v2f two = vbc(2.0f);

#pragma unroll 1
    for (int s = 1; s <= KSTEPS; ++s) {
        const v2f (*rb)[TS + 1] = sb[(s - 1) & 1];
        v2f (*wb)[TS + 1] = sb[s & 1];
        // per-step source value from LDS (joins the lgkm queue with the
        // row reads; waited by the compiler-inserted lgkmcnt before use)
        float sv = sigl[s - 1];
        v2f vsig; vsig[0] = 0.0f; vsig[1] = sv;

        // 3x5 window: own row + DPP side cols; rows +-1 from LDS (6 b64)
        // with their side cols via DPP of the loaded values.
        v2f vm[5], vc[5], vp[5];
        vc[1] = cur[0]; vc[2] = cur[1]; vc[3] = cur[2];
        vc[0] = dpp_shift<ROW_SHR1>(cur[0], cur[2]);
        vc[4] = dpp_shift<ROW_SHL1>(cur[2], cur[0]);
        {
            v2f a0 = rb[rm][c0], a1 = rb[rm][c0 + 1], a2 = rb[rm][c0 + 2];
            vm[1] = a0; vm[2] = a1; vm[3] = a2;
            vm[0] = dpp_shift<ROW_SHR1>(a0, a2);
            vm[4] = dpp_shift<ROW_SHL1>(a2, a0);
        }
        {
            v2f b0 = rb[rp][c0], b1 = rb[rp][c0 + 1], b2 = rb[rp][c0 + 2];
            vp[1] = b0; vp[2] = b1; vp[3] = b2;
            vp[0] = dpp_shift<ROW_SHR1>(b0, b2);
            vp[4] = dpp_shift<ROW_SHL1>(b2, b0);
        }

        // horizontal differences for cross-derivs (rows rm, rp only)
        v2f dhm[3], dhp[3];
#pragma unroll
        for (int j = 0; j < 3; ++j) {
            dhm[j] = vm[j + 2] - vm[j];
            dhp[j] = vp[j + 2] - vp[j];
        }

#pragma unroll
        for (int j = 0; j < 3; ++j) {
            v2f c = vc[j + 1];
            v2f sxx = vfma(m2, c, vm[j + 1] + vp[j + 1]);  // pk
            v2f syy = vfma(m2, c, vc[j] + vc[j + 2]);      // pk
            v2f sxy = qt * (dhp[j] - dhm[j]);              // pk

            // t4 = {2*sxy.x + sxx.y, sxx.x}; t5 = {syy.y, 2*sxy.y + syy.x}
            v2f t4 = vfma(c20, vbc(sxy[0]), vswap(sxx));
            v2f t5 = vfma(c02, vbc(sxy[1]), vswap(syy));
            // L = {lux, luy}
            v2f Lv = ca[j] * sxx;
            Lv = vfma(cb[j], syy, Lv);
            Lv = vfma(vbc(a12p66[j]), vswap(sxy), Lv);
            Lv = vfma(vbc(a16[j]), t4, Lv);
            Lv = vfma(vbc(a26[j]), t5, Lv);
            // source on y only: {lux, sig*gs + luy} (exact: 0*gs+lux)
            Lv = vfma(vsig, vbc(gs[j]), Lv);
            // n = fma(2, c, L) - old
            v2f n = vfma(two, c, Lv) - old_[j];
            old_[j] = c;
            cur[j] = n;
        }

        // frame output at global t = t0 + s - 1; t%4==3 <=> s%4==0
        // (fire-and-forget: the step barrier does NOT drain vmcnt)
        if ((s & 3) == 0 && owned) {
            int f = 3 * L + (s >> 2) - 1;
            float* oux = out + (size_t)f * NPT;
            float* ouy = out + (size_t)(NFRAMES + f) * NPT;
#pragma unroll
            for (int j = 0; j < 3; ++j) {
                oux[gidx[j]] = cur[j][0];
                ouy[gidx[j]] = cur[j][1];
            }
        }

        // publish new values; final step's publish + barrier are dead
        if (s < KSTEPS) {
#pragma unroll
            for (int j = 0; j < 3; ++j)
                wb[r0][c0 + j] = cur[j];
            LDS_BARRIER();
        }
    }

    if (owned) {
#pragma unroll
        for (int j = 0; j < 3; ++j) {
            float4 st = make_float4(cur[j][0], cur[j][1], old_[j][0], old_[j][1]);
            outS[gidx[j]] = st;
        }
    }
}

extern "C" void kernel_launch(void* const* d_in, const int* in_sizes, int n_in,
                              void* d_out, int out_size, void* d_ws, size_t ws_size,
                              hipStream_t stream) {
    const float* lc11  = (const float*)d_in[0];
    const float* lc12  = (const float*)d_in[1];
    const float* lc16  = (const float*)d_in[2];
    const float* lc22  = (const float*)d_in[3];
    const float* lc26  = (const float*)d_in[4];
    const float* lc66  = (const float*)d_in[5];
    const float* gauss = (const float*)d_in[6];
    const float* sig   = (const float*)d_in[7];

    float* ws  = (float*)d_ws;
    float* out = (float*)d_out;

    setup_kernel<<<(NPT + 255) / 256, 256, 0, stream>>>(lc11, lc12, lc16, lc22,
                                                        lc26, lc66, gauss, ws);

    float4* set0 = (float4*)(ws + 8 * (size_t)NPT);
    float4* set1 = (float4*)(ws + 12 * (size_t)NPT);

    dim3 grid(NXg / OWN, NYg / OWN);  // 16x16 = 256 blocks, 1 per CU, 12 waves
    for (int L = 0; L < NLAUNCH; ++L) {
        float4* iS = (L & 1) ? set1 : set0;
        float4* oS = (L & 1) ? set0 : set1;
        fused_kernel<<<grid, NTH, 0, stream>>>(ws, sig, iS, oS, out, L);
    }
}

// Round 10
// 295.608 us; speedup vs baseline: 1.0941x; 1.0941x over previous
//
#include <hip/hip_runtime.h>

// Spatially varying anisotropic 2D elastic wave sim, 384x384, 192 steps.
// Round 17: R15 (293.4us, best) + live-trapezoid wave skipping.
//  - R16 showed rolled loop is 30us WORSE -> full unroll restored.
//  - NEW: step-s compute is wrapped in if(tx>=s && tx<48-s). A cell at
//    row r needs a correct step-s value only if it can still influence
//    the owned core [12,36) at an output step; the widest cone (step-12
//    state) gives live rows [s, 48-s). Rows are wave-aligned (wave = 4
//    rows x all 48 cols), s is a literal (full unroll) -> wave-uniform
//    branch, s_cbranch_execz skips whole waves: 2 dead @s>=4, 4 @s>=8,
//    6 @s=12 (~21% of wave-issue + matching LDS burst share).
//  - Frozen waves still execute the barrier (required) but skip reads,
//    stencil, frame output, and publish. Safety: row r's last publish
//    (at its last live step s=r, buffer parity s&1) is exactly what the
//    row r+1 thread reads at step r+1; rows < s are never read by any
//    live thread afterward. Owned rows [12,36) are live at every s<=12
//    (12>=s and 35<48-s at s=12: [12,36) exactly).
// Everything else bit-identical to R15.

typedef float v2f __attribute__((ext_vector_type(2)));

#define NXg 384
#define NYg 384
#define NPT (NXg * NYg)
#define NFRAMES 48

#define OWN 24
#define HALO 12
#define TS 48
#define KSTEPS 12
#define NLAUNCH 16
#define NTH 768          // 16 wide x 48 tall threads, 12 waves
#define TROW 16

#define H_   1e-4
#define DT_  5e-9
#define RHO_ 1610.0

#define B11_LO 5e10f
#define B11_HI 2.5e11f
#define B22_LO 5e9f
#define B22_HI 5e10f
#define B12_LO 5e9f
#define B12_HI 5e10f
#define B16_LO 0.0f
#define B16_HI 6e10f
#define B26_LO 0.0f
#define B26_HI 2e10f
#define B66_LO 5e9f
#define B66_HI 3e10f

#define ROW_SHR1 0x111   // dst[lane] = src[lane-1] within 16-lane row
#define ROW_SHL1 0x101   // dst[lane] = src[lane+1] within 16-lane row

static __device__ __constant__ float kScale  = (float)(DT_ * DT_ / (H_ * H_) / RHO_);
static __device__ __constant__ float kSrcScl = (float)(DT_ * DT_ / RHO_);

__device__ __forceinline__ float clipf(float v, float lo, float hi) {
    return fminf(fmaxf(v, lo), hi);
}
__device__ __forceinline__ v2f vfma(v2f a, v2f b, v2f c) {
    return __builtin_elementwise_fma(a, b, c);
}
__device__ __forceinline__ v2f vbc(float s) { v2f r; r[0] = s; r[1] = s; return r; }
__device__ __forceinline__ v2f vswap(v2f a) { return __builtin_shufflevector(a, a, 1, 0); }

// in-wave halo import: neighbor lane's v2f via 2x v_mov_dpp.
// Invalid lanes (16-lane-row edge) receive 'oldv' == the rim-clamp value.
template <int CTRL>
__device__ __forceinline__ v2f dpp_shift(v2f oldv, v2f src) {
    union { v2f v; int i[2]; } o, s, r;
    o.v = oldv; s.v = src;
    r.i[0] = __builtin_amdgcn_update_dpp(o.i[0], s.i[0], CTRL, 0xf, 0xf, false);
    r.i[1] = __builtin_amdgcn_update_dpp(o.i[1], s.i[1], CTRL, 0xf, 0xf, false);
    return r.v;
}

// barrier that only waits LDS (no vmcnt drain); memory clobber pins ordering
#define LDS_BARRIER() asm volatile("s_waitcnt lgkmcnt(0)\n\ts_barrier" ::: "memory")

// ws float layout:
// [0..4NPT):   C0 = float4{A11, A22, A12p66, A16}  (pre-scaled)
// [4NPT..8NPT):C1 = float4{A26, A66, GS, 0}
// [8NPT..12NPT):  state set0: float4{cur.x, cur.y, old.x, old.y}
// [12NPT..16NPT): state set1

__global__ __launch_bounds__(256)
void setup_kernel(const float* __restrict__ lc11, const float* __restrict__ lc12,
                  const float* __restrict__ lc16, const float* __restrict__ lc22,
                  const float* __restrict__ lc26, const float* __restrict__ lc66,
                  const float* __restrict__ gauss, float* __restrict__ ws) {
    int i = blockIdx.x * blockDim.x + threadIdx.x;
    if (i >= NPT) return;
    float C11 = clipf(expf(lc11[i]), B11_LO, B11_HI);
    float C12 = clipf(expf(lc12[i]), B12_LO, B12_HI);
    float C16 = clipf(expf(lc16[i]), B16_LO, B16_HI);
    float C22 = clipf(expf(lc22[i]), B22_LO, B22_HI);
    float C26 = clipf(expf(lc26[i]), B26_LO, B26_HI);
    float C66 = clipf(expf(lc66[i]), B66_LO, B66_HI);
    float s = kScale;
    float4* C0 = (float4*)ws;
    float4* C1 = (float4*)(ws + 4 * (size_t)NPT);
    C0[i] = make_float4(C11 * s, C22 * s, (C12 + C66) * s, C16 * s);
    C1[i] = make_float4(C26 * s, C66 * s, gauss[i] * kSrcScl, 0.0f);
    float4* s0 = (float4*)(ws + 8 * (size_t)NPT);
    s0[i] = make_float4(0.0f, 0.0f, 0.0f, 0.0f);
}

__global__ __launch_bounds__(NTH)
void fused_kernel(const float* __restrict__ ws, const float* __restrict__ sig,
                  const float4* __restrict__ inS, float4* __restrict__ outS,
                  float* __restrict__ out, int L) {
    __shared__ v2f sb[2][TS][TS + 1];

    const int tid = threadIdx.x;
    const int tx = tid >> 4;          // 0..47 cell row
    const int ty = tid & 15;          // 0..15, 3 cells wide each
    const int r0 = tx;
    const int c0 = 3 * ty;
    const int gx0 = blockIdx.y * OWN - HALO;
    const int gy0 = blockIdx.x * OWN - HALO;

    const float4* __restrict__ C0 = (const float4*)ws;
    const float4* __restrict__ C1 = (const float4*)(ws + 4 * (size_t)NPT);

    v2f cur[3], old_[3];
    v2f ca[3], cb[3];                       // {A11,A66}, {A66,A22}
    float a12p66[3], a16[3], a26[3], gs[3];
    int gidx[3];

#pragma unroll
    for (int j = 0; j < 3; ++j) {
        int gx = gx0 + r0;
        int gy = gy0 + c0 + j;
        bool d = (unsigned)gx < (unsigned)NXg && (unsigned)gy < (unsigned)NYg;
        int g = d ? gx * NYg + gy : 0;
        gidx[j] = g;
        float4 st = d ? inS[g] : make_float4(0, 0, 0, 0);
        v2f c; c[0] = st.x; c[1] = st.y;
        v2f o; o[0] = st.z; o[1] = st.w;
        cur[j] = c; old_[j] = o;
        float4 k0 = d ? C0[g] : make_float4(0, 0, 0, 0);
        float4 k1 = d ? C1[g] : make_float4(0, 0, 0, 0);
        v2f t; t[0] = k0.x; t[1] = k1.y; ca[j] = t;   // {A11, A66}
        v2f u; u[0] = k1.y; u[1] = k0.y; cb[j] = u;   // {A66, A22}
        a12p66[j] = k0.z; a16[j] = k0.w; a26[j] = k1.x; gs[j] = k1.z;
    }

    // preload all step source values; step loop FULLY UNROLLED -> registers
    const int t0 = L * KSTEPS;
    float sigv[KSTEPS];
#pragma unroll
    for (int k = 0; k < KSTEPS; ++k) sigv[k] = sig[t0 + k];

    // clamped vertical halo rows (trapezoid garbage-tolerance at rim)
    const int rm = (r0 > 0) ? r0 - 1 : 0;
    const int rp = (r0 + 1 < TS) ? r0 + 1 : TS - 1;

    // owned core: rows [12,36) -> tx in [12,36); cols [12,36) -> ty in [4,12)
    const bool owned = (tx >= 12) && (tx < 36) && (ty >= 4) && (ty < 12);

    // publish initial values into buffer 0
#pragma unroll
    for (int j = 0; j < 3; ++j)
        sb[0][r0][c0 + j] = cur[j];
    LDS_BARRIER();

    v2f c20; c20[0] = 2.0f; c20[1] = 0.0f;
    v2f c02; c02[0] = 0.0f; c02[1] = 2.0f;
    const v2f m2 = vbc(-2.0f);
    const v2f qt = vbc(0.25f);
    const v2f two = vbc(2.0f);

#pragma unroll
    for (int s = 1; s <= KSTEPS; ++s) {
        const v2f (*rb)[TS + 1] = sb[(s - 1) & 1];
        v2f (*wb)[TS + 1] = sb[s & 1];

        // live trapezoid: only rows [s, 48-s) can still influence an
        // output. s is a literal (full unroll); rows are wave-aligned ->
        // dead waves skip reads+compute+publish entirely (execz branch).
        if (tx >= s && tx < TS - s) {
            v2f vsig; vsig[0] = 0.0f; vsig[1] = sigv[s - 1];

            // 3x5 window: own row + DPP side cols; rows +-1 from LDS
            // (6 b64) with their side cols via DPP of the loaded values.
            v2f vm[5], vc[5], vp[5];
            vc[1] = cur[0]; vc[2] = cur[1]; vc[3] = cur[2];
            vc[0] = dpp_shift<ROW_SHR1>(cur[0], cur[2]);
            vc[4] = dpp_shift<ROW_SHL1>(cur[2], cur[0]);
            {
                v2f a0 = rb[rm][c0], a1 = rb[rm][c0 + 1], a2 = rb[rm][c0 + 2];
                vm[1] = a0; vm[2] = a1; vm[3] = a2;
                vm[0] = dpp_shift<ROW_SHR1>(a0, a2);
                vm[4] = dpp_shift<ROW_SHL1>(a2, a0);
            }
            {
                v2f b0 = rb[rp][c0], b1 = rb[rp][c0 + 1], b2 = rb[rp][c0 + 2];
                vp[1] = b0; vp[2] = b1; vp[3] = b2;
                vp[0] = dpp_shift<ROW_SHR1>(b0, b2);
                vp[4] = dpp_shift<ROW_SHL1>(b2, b0);
            }

            // horizontal differences for cross-derivs (rows rm, rp only)
            v2f dhm[3], dhp[3];
#pragma unroll
            for (int j = 0; j < 3; ++j) {
                dhm[j] = vm[j + 2] - vm[j];
                dhp[j] = vp[j + 2] - vp[j];
            }

#pragma unroll
            for (int j = 0; j < 3; ++j) {
                v2f c = vc[j + 1];
                v2f sxx = vfma(m2, c, vm[j + 1] + vp[j + 1]);  // pk
                v2f syy = vfma(m2, c, vc[j] + vc[j + 2]);      // pk
                v2f sxy = qt * (dhp[j] - dhm[j]);              // pk

                // t4 = {2*sxy.x + sxx.y, sxx.x}; t5 = {syy.y, 2*sxy.y + syy.x}
                v2f t4 = vfma(c20, vbc(sxy[0]), vswap(sxx));
                v2f t5 = vfma(c02, vbc(sxy[1]), vswap(syy));
                // L = {lux, luy}
                v2f Lv = ca[j] * sxx;
                Lv = vfma(cb[j], syy, Lv);
                Lv = vfma(vbc(a12p66[j]), vswap(sxy), Lv);
                Lv = vfma(vbc(a16[j]), t4, Lv);
                Lv = vfma(vbc(a26[j]), t5, Lv);
                // source on y only: {lux, sig*gs + luy} (exact: 0*gs+lux)
                Lv = vfma(vsig, vbc(gs[j]), Lv);
                // n = fma(2, c, L) - old
                v2f n = vfma(two, c, Lv) - old_[j];
                old_[j] = c;
                cur[j] = n;
            }

            // frame output at global t = t0 + s - 1; t%4==3 <=> s%4==0
            // owned rows are live at every s<=12, so this stays in-branch.
            if ((s & 3) == 0 && owned) {
                int f = 3 * L + (s >> 2) - 1;
                float* oux = out + (size_t)f * NPT;
                float* ouy = out + (size_t)(NFRAMES + f) * NPT;
#pragma unroll
                for (int j = 0; j < 3; ++j) {
                    oux[gidx[j]] = cur[j][0];
                    ouy[gidx[j]] = cur[j][1];
                }
            }

            // publish new values (dead rows' slots are never read again)
            if (s < KSTEPS) {
#pragma unroll
                for (int j = 0; j < 3; ++j)
                    wb[r0][c0 + j] = cur[j];
            }
        }

        // ONE lgkm-only barrier per step -- ALL waves, including frozen
        // ones, must arrive. Final step's barrier is dead -> skipped.
        if (s < KSTEPS) {
            LDS_BARRIER();
        }
    }

    if (owned) {
#pragma unroll
        for (int j = 0; j < 3; ++j) {
            float4 st = make_float4(cur[j][0], cur[j][1], old_[j][0], old_[j][1]);
            outS[gidx[j]] = st;
        }
    }
}

extern "C" void kernel_launch(void* const* d_in, const int* in_sizes, int n_in,
                              void* d_out, int out_size, void* d_ws, size_t ws_size,
                              hipStream_t stream) {
    const float* lc11  = (const float*)d_in[0];
    const float* lc12  = (const float*)d_in[1];
    const float* lc16  = (const float*)d_in[2];
    const float* lc22  = (const float*)d_in[3];
    const float* lc26  = (const float*)d_in[4];
    const float* lc66  = (const float*)d_in[5];
    const float* gauss = (const float*)d_in[6];
    const float* sig   = (const float*)d_in[7];

    float* ws  = (float*)d_ws;
    float* out = (float*)d_out;

    setup_kernel<<<(NPT + 255) / 256, 256, 0, stream>>>(lc11, lc12, lc16, lc22,
                                                        lc26, lc66, gauss, ws);

    float4* set0 = (float4*)(ws + 8 * (size_t)NPT);
    float4* set1 = (float4*)(ws + 12 * (size_t)NPT);

    dim3 grid(NXg / OWN, NYg / OWN);  // 16x16 = 256 blocks, 1 per CU, 12 waves
    for (int L = 0; L < NLAUNCH; ++L) {
        float4* iS = (L & 1) ? set1 : set0;
        float4* oS = (L & 1) ? set0 : set1;
        fused_kernel<<<grid, NTH, 0, stream>>>(ws, sig, iS, oS, out, L);
    }
}